// Round 1
// baseline (1561.293 us; speedup 1.0000x reference)
//
#include <hip/hip_runtime.h>
#include <hip/hip_bf16.h>
#include <math.h>

#define NB 8
#define LSEQ 5000
#define DIN 12
#define HCH 256
#define N2C 32
#define NLAY 6
#define G2C 512
#define TTC 64
#define NCH 79
#define LPAD 5120

typedef __attribute__((ext_vector_type(8))) short bf8v;
typedef __attribute__((ext_vector_type(8))) unsigned short us8v;
typedef __attribute__((ext_vector_type(4))) float f32x4;

#define MFMA16(a,b,c) __builtin_amdgcn_mfma_f32_16x16x32_bf16((a),(b),(c),0,0,0)

static __device__ __forceinline__ unsigned short f2bf(float f){
  unsigned int u = __float_as_uint(f);
  u = u + 0x7FFFu + ((u >> 16) & 1u);
  return (unsigned short)(u >> 16);
}
static __device__ __forceinline__ float bf2f(unsigned short s){
  return __uint_as_float(((unsigned int)s) << 16);
}
static __device__ __forceinline__ bf8v pack8(float4 a, float4 b){
  bf8v r;
  r[0]=(short)f2bf(a.x); r[1]=(short)f2bf(a.y); r[2]=(short)f2bf(a.z); r[3]=(short)f2bf(a.w);
  r[4]=(short)f2bf(b.x); r[5]=(short)f2bf(b.y); r[6]=(short)f2bf(b.z); r[7]=(short)f2bf(b.w);
  return r;
}
static __device__ __forceinline__ float gelu_f(float x){
  return 0.5f*x*(1.0f + erff(x*0.70710678118654752f));
}
static __device__ __forceinline__ float sigm(float x){
  return 1.0f/(1.0f + expf(-x));
}

// ---------------- precompute ----------------

__global__ __launch_bounds__(256) void kp_params(
    const float* __restrict__ log_dt, const float* __restrict__ lAr,
    const float* __restrict__ A_im, const float* __restrict__ C_re,
    const float* __restrict__ C_im,
    float* __restrict__ p_ar, float* __restrict__ p_ai,
    float* __restrict__ p_cer, float* __restrict__ p_cei,
    float* __restrict__ p_wtr, float* __restrict__ p_wti)
{
  int idx = blockIdx.x*256 + threadIdx.x;        // NLAY*HCH*N2C
  int lh = idx >> 5;
  float dt = expf(log_dt[lh]);
  float Are = -expf(lAr[idx]);
  float Aim = A_im[idx];
  float ar = Are*dt, ai = Aim*dt;
  float er = expf(ar);
  float wr = er*cosf(ai), wi = er*sinf(ai);
  float inv = 1.0f/(Are*Are + Aim*Aim);
  float tr = ((wr-1.0f)*Are + wi*Aim)*inv;
  float ti = (wi*Are - (wr-1.0f)*Aim)*inv;
  p_cer[idx] = C_re[idx]*tr - C_im[idx]*ti;
  p_cei[idx] = C_re[idx]*ti + C_im[idx]*tr;
  p_ar[idx] = ar; p_ai[idx] = ai;
  float eT = expf(ar*64.0f);
  p_wtr[idx] = eT*cosf(ai*64.0f);
  p_wti[idx] = eT*sinf(ai*64.0f);
}

__global__ __launch_bounds__(256) void kp_kk(
    const float* __restrict__ p_ar, const float* __restrict__ p_ai,
    const float* __restrict__ p_cer, const float* __restrict__ p_cei,
    float* __restrict__ kk)
{
  int idx = blockIdx.x*256 + threadIdx.x;        // NLAY*HCH*TTC
  int d = idx & 63, lh = idx >> 6;
  int base = lh*N2C;
  float fd = (float)d;
  float s = 0.0f;
  for (int n=0; n<N2C; n++){
    float ar = p_ar[base+n], ai = p_ai[base+n];
    float e = expf(ar*fd);
    float pr = e*cosf(ai*fd), pi = e*sinf(ai*fd);
    s += p_cer[base+n]*pr - p_cei[base+n]*pi;
  }
  kk[idx] = 2.0f*s;
}

// A2: per (layer,h): 64x128: cols 0..63 = Toeplitz k[t-j] (j<=t), cols 64..127 = +-2*CW
__global__ __launch_bounds__(256) void kp_A2(
    const float* __restrict__ p_ar, const float* __restrict__ p_ai,
    const float* __restrict__ p_cer, const float* __restrict__ p_cei,
    const float* __restrict__ kk, unsigned short* __restrict__ A2b)
{
  int idx = blockIdx.x*256 + threadIdx.x;        // NLAY*HCH*TTC*128
  int kcol = idx & 127;
  int t = (idx >> 7) & 63;
  int lh = idx >> 13;
  float v;
  if (kcol < 64){
    v = (kcol <= t) ? kk[lh*64 + (t - kcol)] : 0.0f;
  } else {
    int q = kcol - 64, n = q >> 1;
    int p = lh*N2C + n;
    float fp = (float)(t+1);
    float e = expf(p_ar[p]*fp);
    float pr = e*cosf(p_ai[p]*fp), pi = e*sinf(p_ai[p]*fp);
    float cer = p_cer[p], cei = p_cei[p];
    v = (q&1) ? -2.0f*(cer*pi + cei*pr) : 2.0f*(cer*pr - cei*pi);
  }
  A2b[idx] = f2bf(v);
}

// Vm: per (layer,h): 64x64: row q=2n+{re,im}, col j: w_n^{63-j}
__global__ __launch_bounds__(256) void kp_Vm(
    const float* __restrict__ p_ar, const float* __restrict__ p_ai,
    unsigned short* __restrict__ Vmb)
{
  int idx = blockIdx.x*256 + threadIdx.x;        // NLAY*HCH*TTC*TTC
  int j = idx & 63;
  int q = (idx >> 6) & 63;
  int lh = idx >> 12;
  int n = q >> 1;
  int p = lh*N2C + n;
  float fp = (float)(63 - j);
  float e = expf(p_ar[p]*fp);
  float pr = e*cosf(p_ai[p]*fp), pi = e*sinf(p_ai[p]*fp);
  Vmb[idx] = f2bf((q&1) ? pi : pr);
}

// pair-interleaved W + bias: row 2h <- out_w[h], row 2h+1 <- out_w[h+HCH]
__global__ __launch_bounds__(256) void kp_Wp(
    const float* __restrict__ out_w, const float* __restrict__ out_b,
    unsigned short* __restrict__ Wpb, float* __restrict__ bp)
{
  int idx = blockIdx.x*256 + threadIdx.x;        // NLAY*G2C*HCH
  int hcol = idx & 255;
  int g2 = (idx >> 8) & 511;
  int li = idx >> 17;
  int src = (g2 >> 1) + ((g2 & 1) ? HCH : 0);
  Wpb[idx] = f2bf(out_w[((size_t)li*G2C + src)*HCH + hcol]);
  if (hcol == 0) bp[li*G2C + g2] = out_b[li*G2C + src];
}

// ---------------- pre-projection ----------------

__global__ __launch_bounds__(256) void k_preproj(
    const float* __restrict__ x, const float* __restrict__ pre_w,
    const float* __restrict__ pre_b, float* __restrict__ hbuf)
{
  int l = blockIdx.x*256 + threadIdx.x;
  int hc = blockIdx.y, b = blockIdx.z;
  if (l >= LSEQ) return;
  const float* xr = x + (size_t)(b*LSEQ + l)*DIN;
  const float* wr = pre_w + hc*DIN;
  float acc = pre_b[hc];
  #pragma unroll
  for (int d=0; d<DIN; d++) acc += xr[d]*wr[d];
  hbuf[(size_t)(b*HCH + hc)*LSEQ + l] = acc;
}

// ---------------- S1: chunk end-states via MFMA ----------------

__global__ __launch_bounds__(320) void k_s1(
    const unsigned short* __restrict__ Vm, const float* __restrict__ hbuf,
    float* __restrict__ ES, int layer)
{
  int bh = blockIdx.x;
  int hc = bh & (HCH-1);
  int tid = threadIdx.x, wid = tid>>6, lane = tid&63;
  int craw = wid*16 + (lane&15);
  int c = craw < NCH ? craw : NCH-1;
  const unsigned short* Ap = Vm + (size_t)(layer*HCH + hc)*TTC*TTC + (size_t)(lane&15)*TTC;
  const float* up = hbuf + (size_t)bh*LSEQ + (size_t)c*64;
  int krow = (lane>>4)*8;
  f32x4 a0={0,0,0,0}, a1={0,0,0,0}, a2={0,0,0,0}, a3={0,0,0,0};
  #pragma unroll
  for (int ks=0; ks<2; ks++){
    int kb = ks*32 + krow;
    float4 u0 = *(const float4*)(up + kb);
    float4 u1 = *(const float4*)(up + kb + 4);
    bf8v bfr = pack8(u0,u1);
    a0 = MFMA16(*(const bf8v*)(Ap + 0*16*TTC + kb), bfr, a0);
    a1 = MFMA16(*(const bf8v*)(Ap + 1*16*TTC + kb), bfr, a1);
    a2 = MFMA16(*(const bf8v*)(Ap + 2*16*TTC + kb), bfr, a2);
    a3 = MFMA16(*(const bf8v*)(Ap + 3*16*TTC + kb), bfr, a3);
  }
  if (craw < NCH){
    float* ep = ES + ((size_t)bh*NCH + craw)*64 + (lane>>4)*4;
    *(f32x4*)(ep +  0) = a0;
    *(f32x4*)(ep + 16) = a1;
    *(f32x4*)(ep + 32) = a2;
    *(f32x4*)(ep + 48) = a3;
  }
}

// ---------------- S2: sequential chunk scan (in-place E->S) ----------------

__global__ __launch_bounds__(256) void k_s2(
    const float* __restrict__ wtr, const float* __restrict__ wti,
    float* __restrict__ ES, int layer)
{
  int t = blockIdx.x*256 + threadIdx.x;          // NB*HCH*32
  int n = t & 31, bh = t >> 5;
  int hc = bh & (HCH-1);
  float wr = wtr[(layer*HCH + hc)*N2C + n];
  float wi = wti[(layer*HCH + hc)*N2C + n];
  float sr = 0.0f, si = 0.0f;
  float2* p = (float2*)ES + (size_t)bh*NCH*32 + n;
  #pragma unroll 4
  for (int c=0; c<NCH; c++){
    float2 e = p[(size_t)c*32];
    p[(size_t)c*32] = make_float2(sr, si);
    float nr = wr*sr - wi*si + e.x;
    si = wr*si + wi*sr + e.y;
    sr = nr;
  }
}

// ---------------- S3: per-chunk output = Toeplitz conv + correction, + D*u, gelu ----------------

__global__ __launch_bounds__(320) void k_s3(
    const unsigned short* __restrict__ A2, const float* __restrict__ hbuf,
    const float* __restrict__ ES, const float* __restrict__ Dg,
    unsigned short* __restrict__ yg, int layer)
{
  __shared__ float ybuf[80*64];
  int bh = blockIdx.x;
  int hc = bh & (HCH-1);
  int tid = threadIdx.x, wid = tid>>6, lane = tid&63;
  int craw = wid*16 + (lane&15);
  int c = craw < NCH ? craw : NCH-1;
  const unsigned short* Ap = A2 + (size_t)(layer*HCH + hc)*TTC*128 + (size_t)(lane&15)*128;
  const float* ub = hbuf + (size_t)bh*LSEQ;
  const float* sb = ES + ((size_t)bh*NCH + c)*64;
  int krow = (lane>>4)*8;
  f32x4 acc0={0,0,0,0},acc1={0,0,0,0},acc2={0,0,0,0},acc3={0,0,0,0};
  #pragma unroll
  for (int ks=0; ks<4; ks++){
    int kb = ks*32 + krow;
    const float* src = (ks < 2) ? (ub + (size_t)c*64 + kb) : (sb + (kb - 64));
    float4 u0 = *(const float4*)(src);
    float4 u1 = *(const float4*)(src + 4);
    bf8v bfr = pack8(u0,u1);
    acc0 = MFMA16(*(const bf8v*)(Ap + 0*16*128 + kb), bfr, acc0);
    acc1 = MFMA16(*(const bf8v*)(Ap + 1*16*128 + kb), bfr, acc1);
    acc2 = MFMA16(*(const bf8v*)(Ap + 2*16*128 + kb), bfr, acc2);
    acc3 = MFMA16(*(const bf8v*)(Ap + 3*16*128 + kb), bfr, acc3);
  }
  // hi/lo split on state operand (states can be large; kill bf16 rounding of S)
  #pragma unroll
  for (int ks=2; ks<4; ks++){
    int kb = ks*32 + krow;
    const float* src = sb + (kb - 64);
    float4 u0 = *(const float4*)(src);
    float4 u1 = *(const float4*)(src + 4);
    float4 r0, r1;
    r0.x = u0.x - bf2f(f2bf(u0.x)); r0.y = u0.y - bf2f(f2bf(u0.y));
    r0.z = u0.z - bf2f(f2bf(u0.z)); r0.w = u0.w - bf2f(f2bf(u0.w));
    r1.x = u1.x - bf2f(f2bf(u1.x)); r1.y = u1.y - bf2f(f2bf(u1.y));
    r1.z = u1.z - bf2f(f2bf(u1.z)); r1.w = u1.w - bf2f(f2bf(u1.w));
    bf8v bfr = pack8(r0,r1);
    acc0 = MFMA16(*(const bf8v*)(Ap + 0*16*128 + kb), bfr, acc0);
    acc1 = MFMA16(*(const bf8v*)(Ap + 1*16*128 + kb), bfr, acc1);
    acc2 = MFMA16(*(const bf8v*)(Ap + 2*16*128 + kb), bfr, acc2);
    acc3 = MFMA16(*(const bf8v*)(Ap + 3*16*128 + kb), bfr, acc3);
  }
  float Dv = Dg[layer*HCH + hc];
  int tq = (lane>>4)*4;
  {
    const float* uq = ub + (size_t)craw*64 + tq;
    float* yb = ybuf + craw*64 + tq;
    float4 u4;
    u4 = *(const float4*)(uq + 0);
    yb[ 0] = gelu_f(acc0[0] + Dv*u4.x); yb[ 1] = gelu_f(acc0[1] + Dv*u4.y);
    yb[ 2] = gelu_f(acc0[2] + Dv*u4.z); yb[ 3] = gelu_f(acc0[3] + Dv*u4.w);
    u4 = *(const float4*)(uq + 16);
    yb[16] = gelu_f(acc1[0] + Dv*u4.x); yb[17] = gelu_f(acc1[1] + Dv*u4.y);
    yb[18] = gelu_f(acc1[2] + Dv*u4.z); yb[19] = gelu_f(acc1[3] + Dv*u4.w);
    u4 = *(const float4*)(uq + 32);
    yb[32] = gelu_f(acc2[0] + Dv*u4.x); yb[33] = gelu_f(acc2[1] + Dv*u4.y);
    yb[34] = gelu_f(acc2[2] + Dv*u4.z); yb[35] = gelu_f(acc2[3] + Dv*u4.w);
    u4 = *(const float4*)(uq + 48);
    yb[48] = gelu_f(acc3[0] + Dv*u4.x); yb[49] = gelu_f(acc3[1] + Dv*u4.y);
    yb[50] = gelu_f(acc3[2] + Dv*u4.z); yb[51] = gelu_f(acc3[3] + Dv*u4.w);
  }
  __syncthreads();
  unsigned short* ygp = yg + (size_t)bh*LSEQ;
  #pragma unroll
  for (int pass=0; pass<2; pass++){
    int l0 = (pass*320 + tid)*8;
    if (l0 < LSEQ){
      float4 v0 = *(const float4*)(ybuf + l0);
      float4 v1 = *(const float4*)(ybuf + l0 + 4);
      us8v o;
      o[0]=f2bf(v0.x); o[1]=f2bf(v0.y); o[2]=f2bf(v0.z); o[3]=f2bf(v0.w);
      o[4]=f2bf(v1.x); o[5]=f2bf(v1.y); o[6]=f2bf(v1.z); o[7]=f2bf(v1.w);
      *(us8v*)(ygp + l0) = o;
    }
  }
}

// ---------------- transpose yg[b][h][l] -> ygT[b][l][h] (bf16) ----------------

__global__ __launch_bounds__(256) void k_T(
    const unsigned short* __restrict__ yg, unsigned short* __restrict__ ygT)
{
  __shared__ unsigned short tile[64][72];
  int b = blockIdx.z, h0 = blockIdx.y*64, l0 = blockIdx.x*64;
  int tid = threadIdx.x;
  #pragma unroll
  for (int i=0;i<2;i++){
    int lidx = tid + i*256;
    int row = lidx>>3, c8 = (lidx&7)*8;
    us8v v = 0;
    if (l0 + c8 < LSEQ)
      v = *(const us8v*)(yg + (size_t)(b*HCH + h0 + row)*LSEQ + l0 + c8);
    *(us8v*)(&tile[row][c8]) = v;
  }
  __syncthreads();
  #pragma unroll
  for (int i=0;i<2;i++){
    int widx = tid + i*256;
    int r = widx>>3, h8 = (widx&7)*8;
    int l = l0 + r;
    us8v o = 0;
    if (l < LSEQ){
      #pragma unroll
      for (int e=0;e<8;e++) o[e] = tile[h8+e][r];
    }
    *(us8v*)(ygT + ((size_t)b*LPAD + l)*HCH + h0 + h8) = o;
  }
}

// ---------------- GEMM + GLU + residual + (BN stats) ----------------

template<int DO_STATS>
__global__ __launch_bounds__(256) void k_gemm(
    const unsigned short* __restrict__ Wp, const float* __restrict__ bp,
    const unsigned short* __restrict__ ygT, float* __restrict__ hbuf,
    float* __restrict__ bnsum, float* __restrict__ bnsq, int layer)
{
  int b = blockIdx.z, gt = blockIdx.x, lt = blockIdx.y;
  int tid = threadIdx.x, wid = tid>>6, lane = tid&63;
  int wm = wid>>1, wn = wid&1;
  int g2w = gt*128 + wm*64;
  int lw  = lt*64 + wn*32;
  int krow = (lane>>4)*8, colA = lane&15;
  const unsigned short* Wb = Wp + (size_t)layer*G2C*HCH;
  const unsigned short* Yb = ygT + (size_t)b*LPAD*HCH;
  f32x4 acc[4][2];
  #pragma unroll
  for (int m=0;m<4;m++){ acc[m][0] = (f32x4){0,0,0,0}; acc[m][1] = (f32x4){0,0,0,0}; }
  const unsigned short* b0p = Yb + (size_t)(lw + colA)*HCH + krow;
  const unsigned short* b1p = Yb + (size_t)(lw + 16 + colA)*HCH + krow;
  const unsigned short* a0p = Wb + (size_t)(g2w + colA)*HCH + krow;
  #pragma unroll
  for (int ks=0; ks<8; ks++){
    int kb = ks*32;
    bf8v bf0 = *(const bf8v*)(b0p + kb);
    bf8v bf1 = *(const bf8v*)(b1p + kb);
    #pragma unroll
    for (int m=0;m<4;m++){
      bf8v af = *(const bf8v*)(a0p + (size_t)m*16*HCH + kb);
      acc[m][0] = MFMA16(af, bf0, acc[m][0]);
      acc[m][1] = MFMA16(af, bf1, acc[m][1]);
    }
  }
  float sacc[8], qacc[8];
  if (DO_STATS){
    #pragma unroll
    for (int i=0;i<8;i++){ sacc[i]=0.0f; qacc[i]=0.0f; }
  }
  #pragma unroll
  for (int m=0;m<4;m++){
    int g2r = g2w + m*16 + (lane>>4)*4;
    float4 bias4 = *(const float4*)(bp + layer*G2C + g2r);
    int hc0 = g2r >> 1;
    #pragma unroll
    for (int nf=0; nf<2; nf++){
      int l = lw + nf*16 + colA;
      float a0 = acc[m][nf][0] + bias4.x;
      float g0 = acc[m][nf][1] + bias4.y;
      float a1 = acc[m][nf][2] + bias4.z;
      float g1 = acc[m][nf][3] + bias4.w;
      float z0 = a0 * sigm(g0);
      float z1 = a1 * sigm(g1);
      float r0 = 0.0f, r1 = 0.0f;
      if (l < LSEQ){
        float* pp0 = hbuf + ((size_t)(b*HCH + hc0))*LSEQ + l;
        float* pp1 = pp0 + LSEQ;
        r0 = z0 + pp0[0]; pp0[0] = r0;
        r1 = z1 + pp1[0]; pp1[0] = r1;
      }
      if (DO_STATS){
        sacc[m*2+0] += r0; qacc[m*2+0] += r0*r0;
        sacc[m*2+1] += r1; qacc[m*2+1] += r1*r1;
      }
    }
  }
  if (DO_STATS){
    #pragma unroll
    for (int m=0;m<4;m++){
      #pragma unroll
      for (int zr=0; zr<2; zr++){
        float s = sacc[m*2+zr], q = qacc[m*2+zr];
        s += __shfl_xor(s,1); q += __shfl_xor(q,1);
        s += __shfl_xor(s,2); q += __shfl_xor(q,2);
        s += __shfl_xor(s,4); q += __shfl_xor(q,4);
        s += __shfl_xor(s,8); q += __shfl_xor(q,8);
        if ((lane&15)==0){
          int hc = ((g2w + m*16 + (lane>>4)*4)>>1) + zr;
          atomicAdd(&bnsum[hc], s);
          atomicAdd(&bnsq[hc], q);
        }
      }
    }
  }
}

// ---------------- batchnorm ----------------

__global__ void k_bnfin(const float* __restrict__ bnsum, const float* __restrict__ bnsq,
    const float* __restrict__ gam, const float* __restrict__ bet,
    float* __restrict__ scale, float* __restrict__ shift, int bnidx)
{
  int hc = threadIdx.x;
  const float inv = 1.0f/40000.0f;
  float mean = bnsum[hc]*inv;
  float var = bnsq[hc]*inv - mean*mean;
  float sc = gam[bnidx*HCH + hc] * rsqrtf(var + 1e-5f);
  scale[hc] = sc;
  shift[hc] = bet[bnidx*HCH + hc] - mean*sc;
}

__global__ __launch_bounds__(256) void k_bnapply(float* __restrict__ hbuf,
    const float* __restrict__ scale, const float* __restrict__ shift)
{
  unsigned int i4 = blockIdx.x*256 + threadIdx.x;     // < 2,560,000
  unsigned int e = i4*4u;
  int hc = (int)((e % (unsigned)(HCH*LSEQ)) / (unsigned)LSEQ);
  float sc = scale[hc], sh = shift[hc];
  float4* p = (float4*)hbuf + i4;
  float4 v = *p;
  v.x = v.x*sc + sh; v.y = v.y*sc + sh; v.z = v.z*sc + sh; v.w = v.w*sc + sh;
  *p = v;
}

// ---------------- final transpose h[b][h][l] -> out[b][l][h] ----------------

__global__ __launch_bounds__(256) void k_outT(const float* __restrict__ hbuf,
    float* __restrict__ out)
{
  __shared__ float tile[64][65];
  int b = blockIdx.z, h0 = blockIdx.y*64, l0 = blockIdx.x*64;
  int tid = threadIdx.x;
  #pragma unroll
  for (int i=0;i<4;i++){
    int lidx = tid + i*256;
    int row = lidx>>4, c4 = (lidx&15)*4;
    float4 v = {0,0,0,0};
    if (l0 + c4 < LSEQ)
      v = *(const float4*)(hbuf + (size_t)(b*HCH + h0 + row)*LSEQ + l0 + c4);
    tile[row][c4+0]=v.x; tile[row][c4+1]=v.y; tile[row][c4+2]=v.z; tile[row][c4+3]=v.w;
  }
  __syncthreads();
  #pragma unroll
  for (int i=0;i<4;i++){
    int widx = tid + i*256;
    int r = widx>>4, h4 = (widx&15)*4;
    int l = l0 + r;
    if (l < LSEQ){
      float4 o = { tile[h4+0][r], tile[h4+1][r], tile[h4+2][r], tile[h4+3][r] };
      *(float4*)(out + ((size_t)(b*LSEQ) + l)*HCH + h0 + h4) = o;
    }
  }
}

// ---------------- host ----------------

extern "C" void kernel_launch(void* const* d_in, const int* in_sizes, int n_in,
                              void* d_out, int out_size, void* d_ws, size_t ws_size,
                              hipStream_t stream)
{
  (void)in_sizes; (void)n_in; (void)out_size; (void)ws_size;
  const float* x      = (const float*)d_in[0];
  const float* pre_w  = (const float*)d_in[1];
  const float* pre_b  = (const float*)d_in[2];
  const float* log_dt = (const float*)d_in[3];
  const float* C_re   = (const float*)d_in[4];
  const float* C_im   = (const float*)d_in[5];
  const float* lAr    = (const float*)d_in[6];
  const float* A_im   = (const float*)d_in[7];
  const float* Dg     = (const float*)d_in[8];
  const float* out_w  = (const float*)d_in[9];
  const float* out_b  = (const float*)d_in[10];
  const float* gam    = (const float*)d_in[11];
  const float* bet    = (const float*)d_in[12];
  float* out = (float*)d_out;

  char* ws = (char*)d_ws;
  size_t off = 0;
  auto alloc = [&](size_t bytes)->char*{
    char* p = ws + off;
    off += (bytes + 255) & ~(size_t)255;
    return p;
  };
  float*          hbuf  = (float*)         alloc((size_t)(NB*HCH*LSEQ + 8192)*4);
  unsigned short* yg    = (unsigned short*)alloc((size_t)(NB*HCH*LSEQ + 64)*2);
  unsigned short* ygT   = (unsigned short*)alloc((size_t)NB*LPAD*HCH*2);
  float*          ES    = (float*)         alloc((size_t)((size_t)NB*HCH*NCH*64 + 256)*4);
  float*          p_ar  = (float*)         alloc((size_t)NLAY*HCH*N2C*4);
  float*          p_ai  = (float*)         alloc((size_t)NLAY*HCH*N2C*4);
  float*          p_cer = (float*)         alloc((size_t)NLAY*HCH*N2C*4);
  float*          p_cei = (float*)         alloc((size_t)NLAY*HCH*N2C*4);
  float*          p_wtr = (float*)         alloc((size_t)NLAY*HCH*N2C*4);
  float*          p_wti = (float*)         alloc((size_t)NLAY*HCH*N2C*4);
  float*          kk    = (float*)         alloc((size_t)NLAY*HCH*TTC*4);
  unsigned short* A2b   = (unsigned short*)alloc((size_t)NLAY*HCH*TTC*128*2);
  unsigned short* Vmb   = (unsigned short*)alloc((size_t)NLAY*HCH*TTC*TTC*2);
  unsigned short* Wpb   = (unsigned short*)alloc((size_t)NLAY*G2C*HCH*2);
  float*          bp    = (float*)         alloc((size_t)NLAY*G2C*4);
  float*          bnst  = (float*)         alloc((size_t)4*HCH*4);
  float* bnsum = bnst, *bnsq = bnst + HCH, *bnscale = bnst + 2*HCH, *bnshift = bnst + 3*HCH;

  kp_params<<<(NLAY*HCH*N2C)/256, 256, 0, stream>>>(log_dt, lAr, A_im, C_re, C_im,
      p_ar, p_ai, p_cer, p_cei, p_wtr, p_wti);
  kp_kk<<<(NLAY*HCH*TTC)/256, 256, 0, stream>>>(p_ar, p_ai, p_cer, p_cei, kk);
  kp_A2<<<(NLAY*HCH*TTC*128)/256, 256, 0, stream>>>(p_ar, p_ai, p_cer, p_cei, kk, A2b);
  kp_Vm<<<(NLAY*HCH*TTC*TTC)/256, 256, 0, stream>>>(p_ar, p_ai, Vmb);
  kp_Wp<<<(NLAY*G2C*HCH)/256, 256, 0, stream>>>(out_w, out_b, Wpb, bp);

  k_preproj<<<dim3(20, HCH, NB), 256, 0, stream>>>(x, pre_w, pre_b, hbuf);

  for (int layer=0; layer<NLAY; layer++){
    k_s1<<<NB*HCH, 320, 0, stream>>>(Vmb, hbuf, ES, layer);
    k_s2<<<(NB*HCH*32)/256, 256, 0, stream>>>(p_wtr, p_wti, ES, layer);
    k_s3<<<NB*HCH, 320, 0, stream>>>(A2b, hbuf, ES, Dg, yg, layer);
    k_T<<<dim3(LPAD/64, HCH/64, NB), 256, 0, stream>>>(yg, ygT);
    if ((layer & 1) == 0){
      hipMemsetAsync(bnsum, 0, 2*HCH*sizeof(float), stream);
      k_gemm<1><<<dim3(4, LPAD/64, NB), 256, 0, stream>>>(Wpb, bp, ygT, hbuf, bnsum, bnsq, layer);
      k_bnfin<<<1, HCH, 0, stream>>>(bnsum, bnsq, gam, bet, bnscale, bnshift, layer/2);
      k_bnapply<<<(NB*HCH*LSEQ/4)/256, 256, 0, stream>>>(hbuf, bnscale, bnshift);
    } else {
      k_gemm<0><<<dim3(4, LPAD/64, NB), 256, 0, stream>>>(Wpb, bp, ygT, hbuf, bnsum, bnsq, layer);
    }
  }
  k_outT<<<dim3(79, HCH/64, NB), 256, 0, stream>>>(hbuf, out);
}

// Round 2
// 1199.812 us; speedup vs baseline: 1.3013x; 1.3013x over previous
//
#include <hip/hip_runtime.h>
#include <hip/hip_bf16.h>
#include <math.h>

#define NB 8
#define LSEQ 5000
#define DIN 12
#define HCH 256
#define N2C 32
#define NLAY 6
#define G2C 512
#define TTC 64
#define NCH 79
#define LPAD 5120

typedef __attribute__((ext_vector_type(8))) short bf8v;
typedef __attribute__((ext_vector_type(8))) unsigned short us8v;
typedef __attribute__((ext_vector_type(4))) float f32x4;

#define MFMA16(a,b,c) __builtin_amdgcn_mfma_f32_16x16x32_bf16((a),(b),(c),0,0,0)

static __device__ __forceinline__ unsigned short f2bf(float f){
  unsigned int u = __float_as_uint(f);
  u = u + 0x7FFFu + ((u >> 16) & 1u);
  return (unsigned short)(u >> 16);
}
static __device__ __forceinline__ float bf2f(unsigned short s){
  return __uint_as_float(((unsigned int)s) << 16);
}
static __device__ __forceinline__ bf8v pack8(float4 a, float4 b){
  bf8v r;
  r[0]=(short)f2bf(a.x); r[1]=(short)f2bf(a.y); r[2]=(short)f2bf(a.z); r[3]=(short)f2bf(a.w);
  r[4]=(short)f2bf(b.x); r[5]=(short)f2bf(b.y); r[6]=(short)f2bf(b.z); r[7]=(short)f2bf(b.w);
  return r;
}
static __device__ __forceinline__ float gelu_f(float x){
  return 0.5f*x*(1.0f + erff(x*0.70710678118654752f));
}
static __device__ __forceinline__ float sigm(float x){
  return 1.0f/(1.0f + expf(-x));
}

// ---------------- precompute ----------------

__global__ __launch_bounds__(256) void kp_params(
    const float* __restrict__ log_dt, const float* __restrict__ lAr,
    const float* __restrict__ A_im, const float* __restrict__ C_re,
    const float* __restrict__ C_im,
    float* __restrict__ p_ar, float* __restrict__ p_ai,
    float* __restrict__ p_cer, float* __restrict__ p_cei,
    float* __restrict__ p_wtr, float* __restrict__ p_wti)
{
  int idx = blockIdx.x*256 + threadIdx.x;        // NLAY*HCH*N2C
  int lh = idx >> 5;
  float dt = expf(log_dt[lh]);
  float Are = -expf(lAr[idx]);
  float Aim = A_im[idx];
  float ar = Are*dt, ai = Aim*dt;
  float er = expf(ar);
  float wr = er*cosf(ai), wi = er*sinf(ai);
  float inv = 1.0f/(Are*Are + Aim*Aim);
  float tr = ((wr-1.0f)*Are + wi*Aim)*inv;
  float ti = (wi*Are - (wr-1.0f)*Aim)*inv;
  p_cer[idx] = C_re[idx]*tr - C_im[idx]*ti;
  p_cei[idx] = C_re[idx]*ti + C_im[idx]*tr;
  p_ar[idx] = ar; p_ai[idx] = ai;
  float eT = expf(ar*64.0f);
  p_wtr[idx] = eT*cosf(ai*64.0f);
  p_wti[idx] = eT*sinf(ai*64.0f);
}

__global__ __launch_bounds__(256) void kp_kk(
    const float* __restrict__ p_ar, const float* __restrict__ p_ai,
    const float* __restrict__ p_cer, const float* __restrict__ p_cei,
    float* __restrict__ kk)
{
  int idx = blockIdx.x*256 + threadIdx.x;        // NLAY*HCH*TTC
  int d = idx & 63, lh = idx >> 6;
  int base = lh*N2C;
  float fd = (float)d;
  float s = 0.0f;
  for (int n=0; n<N2C; n++){
    float ar = p_ar[base+n], ai = p_ai[base+n];
    float e = expf(ar*fd);
    float pr = e*cosf(ai*fd), pi = e*sinf(ai*fd);
    s += p_cer[base+n]*pr - p_cei[base+n]*pi;
  }
  kk[idx] = 2.0f*s;
}

// A2: per (layer,h): 64x128: cols 0..63 = Toeplitz k[t-j] (j<=t), cols 64..127 = +-2*CW
__global__ __launch_bounds__(256) void kp_A2(
    const float* __restrict__ p_ar, const float* __restrict__ p_ai,
    const float* __restrict__ p_cer, const float* __restrict__ p_cei,
    const float* __restrict__ kk, unsigned short* __restrict__ A2b)
{
  int idx = blockIdx.x*256 + threadIdx.x;        // NLAY*HCH*TTC*128
  int kcol = idx & 127;
  int t = (idx >> 7) & 63;
  int lh = idx >> 13;
  float v;
  if (kcol < 64){
    v = (kcol <= t) ? kk[lh*64 + (t - kcol)] : 0.0f;
  } else {
    int q = kcol - 64, n = q >> 1;
    int p = lh*N2C + n;
    float fp = (float)(t+1);
    float e = expf(p_ar[p]*fp);
    float pr = e*cosf(p_ai[p]*fp), pi = e*sinf(p_ai[p]*fp);
    float cer = p_cer[p], cei = p_cei[p];
    v = (q&1) ? -2.0f*(cer*pi + cei*pr) : 2.0f*(cer*pr - cei*pi);
  }
  A2b[idx] = f2bf(v);
}

// Vm: per (layer,h): 64x64: row q=2n+{re,im}, col j: w_n^{63-j}
__global__ __launch_bounds__(256) void kp_Vm(
    const float* __restrict__ p_ar, const float* __restrict__ p_ai,
    unsigned short* __restrict__ Vmb)
{
  int idx = blockIdx.x*256 + threadIdx.x;        // NLAY*HCH*TTC*TTC
  int j = idx & 63;
  int q = (idx >> 6) & 63;
  int lh = idx >> 12;
  int n = q >> 1;
  int p = lh*N2C + n;
  float fp = (float)(63 - j);
  float e = expf(p_ar[p]*fp);
  float pr = e*cosf(p_ai[p]*fp), pi = e*sinf(p_ai[p]*fp);
  Vmb[idx] = f2bf((q&1) ? pi : pr);
}

// pair-interleaved W + bias: row 2h <- out_w[h], row 2h+1 <- out_w[h+HCH]
__global__ __launch_bounds__(256) void kp_Wp(
    const float* __restrict__ out_w, const float* __restrict__ out_b,
    unsigned short* __restrict__ Wpb, float* __restrict__ bp)
{
  int idx = blockIdx.x*256 + threadIdx.x;        // NLAY*G2C*HCH
  int hcol = idx & 255;
  int g2 = (idx >> 8) & 511;
  int li = idx >> 17;
  int src = (g2 >> 1) + ((g2 & 1) ? HCH : 0);
  Wpb[idx] = f2bf(out_w[((size_t)li*G2C + src)*HCH + hcol]);
  if (hcol == 0) bp[li*G2C + g2] = out_b[li*G2C + src];
}

// ---------------- pre-projection ----------------

__global__ __launch_bounds__(256) void k_preproj(
    const float* __restrict__ x, const float* __restrict__ pre_w,
    const float* __restrict__ pre_b, float* __restrict__ hbuf)
{
  int l = blockIdx.x*256 + threadIdx.x;
  int hc = blockIdx.y, b = blockIdx.z;
  if (l >= LSEQ) return;
  const float* xr = x + (size_t)(b*LSEQ + l)*DIN;
  const float* wr = pre_w + hc*DIN;
  float acc = pre_b[hc];
  #pragma unroll
  for (int d=0; d<DIN; d++) acc += xr[d]*wr[d];
  hbuf[(size_t)(b*HCH + hc)*LSEQ + l] = acc;
}

// ---------------- S1: chunk end-states via MFMA ----------------

__global__ __launch_bounds__(320) void k_s1(
    const unsigned short* __restrict__ Vm, const float* __restrict__ hbuf,
    float* __restrict__ ES, int layer)
{
  int bh = blockIdx.x;
  int hc = bh & (HCH-1);
  int tid = threadIdx.x, wid = tid>>6, lane = tid&63;
  int craw = wid*16 + (lane&15);
  int c = craw < NCH ? craw : NCH-1;
  const unsigned short* Ap = Vm + (size_t)(layer*HCH + hc)*TTC*TTC + (size_t)(lane&15)*TTC;
  const float* up = hbuf + (size_t)bh*LSEQ + (size_t)c*64;
  int krow = (lane>>4)*8;
  f32x4 a0={0,0,0,0}, a1={0,0,0,0}, a2={0,0,0,0}, a3={0,0,0,0};
  #pragma unroll
  for (int ks=0; ks<2; ks++){
    int kb = ks*32 + krow;
    float4 u0 = *(const float4*)(up + kb);
    float4 u1 = *(const float4*)(up + kb + 4);
    bf8v bfr = pack8(u0,u1);
    a0 = MFMA16(*(const bf8v*)(Ap + 0*16*TTC + kb), bfr, a0);
    a1 = MFMA16(*(const bf8v*)(Ap + 1*16*TTC + kb), bfr, a1);
    a2 = MFMA16(*(const bf8v*)(Ap + 2*16*TTC + kb), bfr, a2);
    a3 = MFMA16(*(const bf8v*)(Ap + 3*16*TTC + kb), bfr, a3);
  }
  if (craw < NCH){
    float* ep = ES + ((size_t)bh*NCH + craw)*64 + (lane>>4)*4;
    *(f32x4*)(ep +  0) = a0;
    *(f32x4*)(ep + 16) = a1;
    *(f32x4*)(ep + 32) = a2;
    *(f32x4*)(ep + 48) = a3;
  }
}

// ---------------- S2: sequential chunk scan (in-place E->S) ----------------

__global__ __launch_bounds__(256) void k_s2(
    const float* __restrict__ wtr, const float* __restrict__ wti,
    float* __restrict__ ES, int layer)
{
  int t = blockIdx.x*256 + threadIdx.x;          // NB*HCH*32
  int n = t & 31, bh = t >> 5;
  int hc = bh & (HCH-1);
  float wr = wtr[(layer*HCH + hc)*N2C + n];
  float wi = wti[(layer*HCH + hc)*N2C + n];
  float sr = 0.0f, si = 0.0f;
  float2* p = (float2*)ES + (size_t)bh*NCH*32 + n;
  #pragma unroll 4
  for (int c=0; c<NCH; c++){
    float2 e = p[(size_t)c*32];
    p[(size_t)c*32] = make_float2(sr, si);
    float nr = wr*sr - wi*si + e.x;
    si = wr*si + wi*sr + e.y;
    sr = nr;
  }
}

// ---------------- S3: per-chunk output = Toeplitz conv + correction, + D*u, gelu ----------------

__global__ __launch_bounds__(320) void k_s3(
    const unsigned short* __restrict__ A2, const float* __restrict__ hbuf,
    const float* __restrict__ ES, const float* __restrict__ Dg,
    unsigned short* __restrict__ yg, int layer)
{
  __shared__ float ybuf[80*64];
  int bh = blockIdx.x;
  int hc = bh & (HCH-1);
  int tid = threadIdx.x, wid = tid>>6, lane = tid&63;
  int craw = wid*16 + (lane&15);
  int c = craw < NCH ? craw : NCH-1;
  const unsigned short* Ap = A2 + (size_t)(layer*HCH + hc)*TTC*128 + (size_t)(lane&15)*128;
  const float* ub = hbuf + (size_t)bh*LSEQ;
  const float* sb = ES + ((size_t)bh*NCH + c)*64;
  int krow = (lane>>4)*8;
  f32x4 acc0={0,0,0,0},acc1={0,0,0,0},acc2={0,0,0,0},acc3={0,0,0,0};
  #pragma unroll
  for (int ks=0; ks<4; ks++){
    int kb = ks*32 + krow;
    const float* src = (ks < 2) ? (ub + (size_t)c*64 + kb) : (sb + (kb - 64));
    float4 u0 = *(const float4*)(src);
    float4 u1 = *(const float4*)(src + 4);
    bf8v bfr = pack8(u0,u1);
    acc0 = MFMA16(*(const bf8v*)(Ap + 0*16*128 + kb), bfr, acc0);
    acc1 = MFMA16(*(const bf8v*)(Ap + 1*16*128 + kb), bfr, acc1);
    acc2 = MFMA16(*(const bf8v*)(Ap + 2*16*128 + kb), bfr, acc2);
    acc3 = MFMA16(*(const bf8v*)(Ap + 3*16*128 + kb), bfr, acc3);
  }
  // hi/lo split on state operand (states can be large; kill bf16 rounding of S)
  #pragma unroll
  for (int ks=2; ks<4; ks++){
    int kb = ks*32 + krow;
    const float* src = sb + (kb - 64);
    float4 u0 = *(const float4*)(src);
    float4 u1 = *(const float4*)(src + 4);
    float4 r0, r1;
    r0.x = u0.x - bf2f(f2bf(u0.x)); r0.y = u0.y - bf2f(f2bf(u0.y));
    r0.z = u0.z - bf2f(f2bf(u0.z)); r0.w = u0.w - bf2f(f2bf(u0.w));
    r1.x = u1.x - bf2f(f2bf(u1.x)); r1.y = u1.y - bf2f(f2bf(u1.y));
    r1.z = u1.z - bf2f(f2bf(u1.z)); r1.w = u1.w - bf2f(f2bf(u1.w));
    bf8v bfr = pack8(r0,r1);
    acc0 = MFMA16(*(const bf8v*)(Ap + 0*16*128 + kb), bfr, acc0);
    acc1 = MFMA16(*(const bf8v*)(Ap + 1*16*128 + kb), bfr, acc1);
    acc2 = MFMA16(*(const bf8v*)(Ap + 2*16*128 + kb), bfr, acc2);
    acc3 = MFMA16(*(const bf8v*)(Ap + 3*16*128 + kb), bfr, acc3);
  }
  float Dv = Dg[layer*HCH + hc];
  int tq = (lane>>4)*4;
  {
    const float* uq = ub + (size_t)craw*64 + tq;
    float* yb = ybuf + craw*64 + tq;
    float4 u4;
    u4 = *(const float4*)(uq + 0);
    yb[ 0] = gelu_f(acc0[0] + Dv*u4.x); yb[ 1] = gelu_f(acc0[1] + Dv*u4.y);
    yb[ 2] = gelu_f(acc0[2] + Dv*u4.z); yb[ 3] = gelu_f(acc0[3] + Dv*u4.w);
    u4 = *(const float4*)(uq + 16);
    yb[16] = gelu_f(acc1[0] + Dv*u4.x); yb[17] = gelu_f(acc1[1] + Dv*u4.y);
    yb[18] = gelu_f(acc1[2] + Dv*u4.z); yb[19] = gelu_f(acc1[3] + Dv*u4.w);
    u4 = *(const float4*)(uq + 32);
    yb[32] = gelu_f(acc2[0] + Dv*u4.x); yb[33] = gelu_f(acc2[1] + Dv*u4.y);
    yb[34] = gelu_f(acc2[2] + Dv*u4.z); yb[35] = gelu_f(acc2[3] + Dv*u4.w);
    u4 = *(const float4*)(uq + 48);
    yb[48] = gelu_f(acc3[0] + Dv*u4.x); yb[49] = gelu_f(acc3[1] + Dv*u4.y);
    yb[50] = gelu_f(acc3[2] + Dv*u4.z); yb[51] = gelu_f(acc3[3] + Dv*u4.w);
  }
  __syncthreads();
  unsigned short* ygp = yg + (size_t)bh*LSEQ;
  #pragma unroll
  for (int pass=0; pass<2; pass++){
    int l0 = (pass*320 + tid)*8;
    if (l0 < LSEQ){
      float4 v0 = *(const float4*)(ybuf + l0);
      float4 v1 = *(const float4*)(ybuf + l0 + 4);
      us8v o;
      o[0]=f2bf(v0.x); o[1]=f2bf(v0.y); o[2]=f2bf(v0.z); o[3]=f2bf(v0.w);
      o[4]=f2bf(v1.x); o[5]=f2bf(v1.y); o[6]=f2bf(v1.z); o[7]=f2bf(v1.w);
      *(us8v*)(ygp + l0) = o;
    }
  }
}

// ---------------- transpose yg[b][h][l] -> ygT[b][l][h] (bf16) ----------------

__global__ __launch_bounds__(256) void k_T(
    const unsigned short* __restrict__ yg, unsigned short* __restrict__ ygT)
{
  __shared__ unsigned short tile[64][72];
  int b = blockIdx.z, h0 = blockIdx.y*64, l0 = blockIdx.x*64;
  int tid = threadIdx.x;
  #pragma unroll
  for (int i=0;i<2;i++){
    int lidx = tid + i*256;
    int row = lidx>>3, c8 = (lidx&7)*8;
    us8v v = 0;
    if (l0 + c8 < LSEQ)
      v = *(const us8v*)(yg + (size_t)(b*HCH + h0 + row)*LSEQ + l0 + c8);
    *(us8v*)(&tile[row][c8]) = v;
  }
  __syncthreads();
  #pragma unroll
  for (int i=0;i<2;i++){
    int widx = tid + i*256;
    int r = widx>>3, h8 = (widx&7)*8;
    int l = l0 + r;
    us8v o = 0;
    if (l < LSEQ){
      #pragma unroll
      for (int e=0;e<8;e++) o[e] = tile[h8+e][r];
    }
    *(us8v*)(ygT + ((size_t)b*LPAD + l)*HCH + h0 + h8) = o;
  }
}

// ---------------- GEMM + GLU + residual + (BN stats): 2-phase LDS-staged ----------------
// Block tile 128(g2) x 128(l), BK=64, K=256 -> 4 K-tiles, double-buffered LDS.
// LDS layout: logical [row][k] 128x64 bf16 (rowstride 128B), phys byte = logical ^ ((row&7)<<4).
// Staged linearly via global_load_lds with inverse-swizzled GLOBAL source (rule #21).

static __device__ __forceinline__ void stage_tile(
    const unsigned short* __restrict__ g, unsigned short* sbuf, int tid)
{
  #pragma unroll
  for (int i=0;i<4;i++){
    int p = i*256 + tid;                 // physical 16B-chunk index in [0,1024)
    int lc = p ^ ((p>>3)&7);             // logical chunk (involution, same row)
    int row = lc>>3, kc = lc&7;
    const unsigned short* ga = g + (size_t)row*HCH + kc*8;
    __builtin_amdgcn_global_load_lds(
        (const __attribute__((address_space(1))) void*)ga,
        (__attribute__((address_space(3))) void*)(sbuf + p*8),
        16, 0, 0);
  }
}

static __device__ __forceinline__ bf8v lds_frag(const unsigned short* sbuf, int row, int k0){
  int byte = (row<<7) + (k0<<1);
  byte ^= ((row&7)<<4);
  return *(const bf8v*)((const char*)sbuf + byte);
}

template<int DO_STATS>
__global__ __launch_bounds__(256, 2) void k_gemm(
    const unsigned short* __restrict__ Wp, const float* __restrict__ bp,
    const unsigned short* __restrict__ ygT, float* __restrict__ hbuf,
    float* __restrict__ bnsum, float* __restrict__ bnsq, int layer)
{
  __shared__ unsigned short smem[4*8192];   // A0,A1,B0,B1 (16KB each)
  int id = blockIdx.x;
  int sw = (id&7)*160 + (id>>3);           // XCD-bijective: gt-siblings same XCD
  int gt = sw&3;
  int r  = sw>>2;                           // [0,320)
  int b  = r/40;
  int lt = r%40;

  int tid = threadIdx.x, wid = tid>>6, lane = tid&63;
  int wm = wid>>1, wn = wid&1;
  int colA = lane&15, krow8 = (lane>>4)*8;

  const unsigned short* Wt = Wp + (size_t)layer*G2C*HCH + (size_t)(gt*128)*HCH;
  const unsigned short* Yt = ygT + (size_t)b*LPAD*HCH + (size_t)(lt*128)*HCH;
  unsigned short* A0 = smem;
  unsigned short* A1 = smem + 8192;
  unsigned short* B0 = smem + 16384;
  unsigned short* B1 = smem + 24576;

  f32x4 acc[4][4];
  #pragma unroll
  for (int m=0;m<4;m++)
    #pragma unroll
    for (int n=0;n<4;n++) acc[m][n] = (f32x4){0,0,0,0};

  stage_tile(Wt, A0, tid);
  stage_tile(Yt, B0, tid);
  __syncthreads();

  #pragma unroll
  for (int kt=0; kt<4; kt++){
    unsigned short* Ac = (kt&1) ? A1 : A0;
    unsigned short* Bc = (kt&1) ? B1 : B0;
    if (kt < 3){
      unsigned short* An = (kt&1) ? A0 : A1;
      unsigned short* Bn = (kt&1) ? B0 : B1;
      stage_tile(Wt + (kt+1)*64, An, tid);
      stage_tile(Yt + (kt+1)*64, Bn, tid);
    }
    #pragma unroll
    for (int ks=0; ks<2; ks++){
      int k0 = ks*32 + krow8;
      bf8v fA[4], fB[4];
      #pragma unroll
      for (int m=0;m<4;m++) fA[m] = lds_frag(Ac, wm*64 + m*16 + colA, k0);
      #pragma unroll
      for (int n=0;n<4;n++) fB[n] = lds_frag(Bc, wn*64 + n*16 + colA, k0);
      #pragma unroll
      for (int m=0;m<4;m++)
        #pragma unroll
        for (int n=0;n<4;n++)
          acc[m][n] = MFMA16(fA[m], fB[n], acc[m][n]);
    }
    __syncthreads();
  }

  float sacc[8], qacc[8];
  if (DO_STATS){
    #pragma unroll
    for (int i=0;i<8;i++){ sacc[i]=0.0f; qacc[i]=0.0f; }
  }
  #pragma unroll
  for (int m=0;m<4;m++){
    int g2r = gt*128 + wm*64 + m*16 + (lane>>4)*4;
    float4 bias4 = *(const float4*)(bp + layer*G2C + g2r);
    int hc0 = g2r >> 1;
    #pragma unroll
    for (int n=0;n<4;n++){
      int l = lt*128 + wn*64 + n*16 + colA;
      float a0 = acc[m][n][0] + bias4.x;
      float g0 = acc[m][n][1] + bias4.y;
      float a1 = acc[m][n][2] + bias4.z;
      float g1 = acc[m][n][3] + bias4.w;
      float z0 = a0 * sigm(g0);
      float z1 = a1 * sigm(g1);
      float r0 = 0.0f, r1 = 0.0f;
      if (l < LSEQ){
        float* pp0 = hbuf + ((size_t)(b*HCH + hc0))*LSEQ + l;
        float* pp1 = pp0 + LSEQ;
        r0 = z0 + pp0[0]; pp0[0] = r0;
        r1 = z1 + pp1[0]; pp1[0] = r1;
      }
      if (DO_STATS){
        sacc[m*2+0] += r0; qacc[m*2+0] += r0*r0;
        sacc[m*2+1] += r1; qacc[m*2+1] += r1*r1;
      }
    }
  }
  if (DO_STATS){
    #pragma unroll
    for (int m=0;m<4;m++){
      #pragma unroll
      for (int zr=0; zr<2; zr++){
        float s = sacc[m*2+zr], q = qacc[m*2+zr];
        s += __shfl_xor(s,1); q += __shfl_xor(q,1);
        s += __shfl_xor(s,2); q += __shfl_xor(q,2);
        s += __shfl_xor(s,4); q += __shfl_xor(q,4);
        s += __shfl_xor(s,8); q += __shfl_xor(q,8);
        if ((lane&15)==0){
          int hc = ((gt*128 + wm*64 + m*16 + (lane>>4)*4)>>1) + zr;
          atomicAdd(&bnsum[hc], s);
          atomicAdd(&bnsq[hc], q);
        }
      }
    }
  }
}

// ---------------- batchnorm ----------------

__global__ void k_bnfin(const float* __restrict__ bnsum, const float* __restrict__ bnsq,
    const float* __restrict__ gam, const float* __restrict__ bet,
    float* __restrict__ scale, float* __restrict__ shift, int bnidx)
{
  int hc = threadIdx.x;
  const float inv = 1.0f/40000.0f;
  float mean = bnsum[hc]*inv;
  float var = bnsq[hc]*inv - mean*mean;
  float sc = gam[bnidx*HCH + hc] * rsqrtf(var + 1e-5f);
  scale[hc] = sc;
  shift[hc] = bet[bnidx*HCH + hc] - mean*sc;
}

__global__ __launch_bounds__(256) void k_bnapply(float* __restrict__ hbuf,
    const float* __restrict__ scale, const float* __restrict__ shift)
{
  unsigned int i4 = blockIdx.x*256 + threadIdx.x;     // < 2,560,000
  unsigned int e = i4*4u;
  int hc = (int)((e % (unsigned)(HCH*LSEQ)) / (unsigned)LSEQ);
  float sc = scale[hc], sh = shift[hc];
  float4* p = (float4*)hbuf + i4;
  float4 v = *p;
  v.x = v.x*sc + sh; v.y = v.y*sc + sh; v.z = v.z*sc + sh; v.w = v.w*sc + sh;
  *p = v;
}

// ---------------- final transpose h[b][h][l] -> out[b][l][h] ----------------

__global__ __launch_bounds__(256) void k_outT(const float* __restrict__ hbuf,
    float* __restrict__ out)
{
  __shared__ float tile[64][65];
  int b = blockIdx.z, h0 = blockIdx.y*64, l0 = blockIdx.x*64;
  int tid = threadIdx.x;
  #pragma unroll
  for (int i=0;i<4;i++){
    int lidx = tid + i*256;
    int row = lidx>>4, c4 = (lidx&15)*4;
    float4 v = {0,0,0,0};
    if (l0 + c4 < LSEQ)
      v = *(const float4*)(hbuf + (size_t)(b*HCH + h0 + row)*LSEQ + l0 + c4);
    tile[row][c4+0]=v.x; tile[row][c4+1]=v.y; tile[row][c4+2]=v.z; tile[row][c4+3]=v.w;
  }
  __syncthreads();
  #pragma unroll
  for (int i=0;i<4;i++){
    int widx = tid + i*256;
    int r = widx>>4, h4 = (widx&15)*4;
    int l = l0 + r;
    if (l < LSEQ){
      float4 o = { tile[h4+0][r], tile[h4+1][r], tile[h4+2][r], tile[h4+3][r] };
      *(float4*)(out + ((size_t)(b*LSEQ) + l)*HCH + h0 + h4) = o;
    }
  }
}

// ---------------- host ----------------

extern "C" void kernel_launch(void* const* d_in, const int* in_sizes, int n_in,
                              void* d_out, int out_size, void* d_ws, size_t ws_size,
                              hipStream_t stream)
{
  (void)in_sizes; (void)n_in; (void)out_size; (void)ws_size;
  const float* x      = (const float*)d_in[0];
  const float* pre_w  = (const float*)d_in[1];
  const float* pre_b  = (const float*)d_in[2];
  const float* log_dt = (const float*)d_in[3];
  const float* C_re   = (const float*)d_in[4];
  const float* C_im   = (const float*)d_in[5];
  const float* lAr    = (const float*)d_in[6];
  const float* A_im   = (const float*)d_in[7];
  const float* Dg     = (const float*)d_in[8];
  const float* out_w  = (const float*)d_in[9];
  const float* out_b  = (const float*)d_in[10];
  const float* gam    = (const float*)d_in[11];
  const float* bet    = (const float*)d_in[12];
  float* out = (float*)d_out;

  char* ws = (char*)d_ws;
  size_t off = 0;
  auto alloc = [&](size_t bytes)->char*{
    char* p = ws + off;
    off += (bytes + 255) & ~(size_t)255;
    return p;
  };
  float*          hbuf  = (float*)         alloc((size_t)(NB*HCH*LSEQ + 8192)*4);
  unsigned short* yg    = (unsigned short*)alloc((size_t)(NB*HCH*LSEQ + 64)*2);
  unsigned short* ygT   = (unsigned short*)alloc((size_t)NB*LPAD*HCH*2);
  float*          ES    = (float*)         alloc((size_t)((size_t)NB*HCH*NCH*64 + 256)*4);
  float*          p_ar  = (float*)         alloc((size_t)NLAY*HCH*N2C*4);
  float*          p_ai  = (float*)         alloc((size_t)NLAY*HCH*N2C*4);
  float*          p_cer = (float*)         alloc((size_t)NLAY*HCH*N2C*4);
  float*          p_cei = (float*)         alloc((size_t)NLAY*HCH*N2C*4);
  float*          p_wtr = (float*)         alloc((size_t)NLAY*HCH*N2C*4);
  float*          p_wti = (float*)         alloc((size_t)NLAY*HCH*N2C*4);
  float*          kk    = (float*)         alloc((size_t)NLAY*HCH*TTC*4);
  unsigned short* A2b   = (unsigned short*)alloc((size_t)NLAY*HCH*TTC*128*2);
  unsigned short* Vmb   = (unsigned short*)alloc((size_t)NLAY*HCH*TTC*TTC*2);
  unsigned short* Wpb   = (unsigned short*)alloc((size_t)NLAY*G2C*HCH*2);
  float*          bp    = (float*)         alloc((size_t)NLAY*G2C*4);
  float*          bnst  = (float*)         alloc((size_t)4*HCH*4);
  float* bnsum = bnst, *bnsq = bnst + HCH, *bnscale = bnst + 2*HCH, *bnshift = bnst + 3*HCH;

  kp_params<<<(NLAY*HCH*N2C)/256, 256, 0, stream>>>(log_dt, lAr, A_im, C_re, C_im,
      p_ar, p_ai, p_cer, p_cei, p_wtr, p_wti);
  kp_kk<<<(NLAY*HCH*TTC)/256, 256, 0, stream>>>(p_ar, p_ai, p_cer, p_cei, kk);
  kp_A2<<<(NLAY*HCH*TTC*128)/256, 256, 0, stream>>>(p_ar, p_ai, p_cer, p_cei, kk, A2b);
  kp_Vm<<<(NLAY*HCH*TTC*TTC)/256, 256, 0, stream>>>(p_ar, p_ai, Vmb);
  kp_Wp<<<(NLAY*G2C*HCH)/256, 256, 0, stream>>>(out_w, out_b, Wpb, bp);

  k_preproj<<<dim3(20, HCH, NB), 256, 0, stream>>>(x, pre_w, pre_b, hbuf);

  for (int layer=0; layer<NLAY; layer++){
    k_s1<<<NB*HCH, 320, 0, stream>>>(Vmb, hbuf, ES, layer);
    k_s2<<<(NB*HCH*32)/256, 256, 0, stream>>>(p_wtr, p_wti, ES, layer);
    k_s3<<<NB*HCH, 320, 0, stream>>>(A2b, hbuf, ES, Dg, yg, layer);
    k_T<<<dim3(LPAD/64, HCH/64, NB), 256, 0, stream>>>(yg, ygT);
    if ((layer & 1) == 0){
      hipMemsetAsync(bnsum, 0, 2*HCH*sizeof(float), stream);
      k_gemm<1><<<1280, 256, 0, stream>>>(Wpb, bp, ygT, hbuf, bnsum, bnsq, layer);
      k_bnfin<<<1, HCH, 0, stream>>>(bnsum, bnsq, gam, bet, bnscale, bnshift, layer/2);
      k_bnapply<<<(NB*HCH*LSEQ/4)/256, 256, 0, stream>>>(hbuf, bnscale, bnshift);
    } else {
      k_gemm<0><<<1280, 256, 0, stream>>>(Wpb, bp, ygT, hbuf, bnsum, bnsq, layer);
    }
  }
  k_outT<<<dim3(79, HCH/64, NB), 256, 0, stream>>>(hbuf, out);
}